// Round 1
// baseline (219.105 us; speedup 1.0000x reference)
//
#include <hip/hip_runtime.h>

typedef unsigned long long ull;

#define NB    16      // batches
#define NPTS  65536   // points per batch
#define NSEED 40      // seeds
#define BPB   16      // blocks per batch
#define TPB   1024    // threads per block (16 waves)
#define NW    16      // waves per block
#define PPT   4       // points per thread
#define R2    0.0025f // RADIUS^2
#define PAYLOAD 0xFFFFFFFFFFFFull
#define DONEG 40ull   // pden tag: != poison 0xAAAA, != gens 1..39
#define MAXACC 12     // max seeds accepted per exchange (>=4 exchanges total)

// pack (value, index): unsigned max == (max value, then smallest index)
__device__ __forceinline__ ull packdi(float v, int idx) {
  return ((ull)__float_as_uint(v) << 16) | (ull)((unsigned)(idx ^ 0xFFFF) & 0xFFFFu);
}

__device__ __forceinline__ ull bmax64(ull x) {
#pragma unroll
  for (int o = 32; o > 0; o >>= 1) {
    ull q = __shfl_xor(x, o, 64);
    x = x > q ? x : q;
  }
  return x;
}

__global__ __launch_bounds__(TPB, 4) void fps_den_kernel(
    const float* __restrict__ pcs, ull* __restrict__ slots,
    ull* __restrict__ pden, float* __restrict__ out)
{
  const int beta = blockIdx.x >> 4;   // batch
  const int blk  = blockIdx.x & 15;   // block within batch
  const int tid  = threadIdx.x;
  const int lane = tid & 63;
  const int wav  = tid >> 6;
  const float* __restrict__ base = pcs + (size_t)beta * (NPTS * 3);

  __shared__ ull   sRedP[2][NW][4];                 // per-wave top-4 keys
  __shared__ float sWx[2][MAXACC], sWy[2][MAXACC], sWz[2][MAXACC]; // accepted batch
  __shared__ int   sWn[2];                          // accepted count
  __shared__ float sSx[NSEED], sSy[NSEED], sSz[NSEED];  // seed history (wave-0 tail)
  __shared__ float sDen[NW][NSEED];                 // density partials / agg reuse
  __shared__ float sV[NB];

  // register-resident points + running min-distance
  float px[PPT], py[PPT], pz[PPT], dist[PPT];
#pragma unroll
  for (int j = 0; j < PPT; ++j) {
    int n = blk * (TPB * PPT) + j * TPB + tid;
    px[j] = base[n * 3 + 0];
    py[j] = base[n * 3 + 1];
    pz[j] = base[n * 3 + 2];
    dist[j] = 1e10f;
  }

  if (tid == 0) {                     // seed 0 = point 0
    float cx = base[0], cy = base[1], cz = base[2];
    sSx[0] = cx; sSy[0] = cy; sSz[0] = cz;
    sWx[0][0] = cx; sWy[0][0] = cy; sWz[0][0] = cz;   // initial pending batch
  }
  __syncthreads();

  // record layout: [beta][parity][blk][slot], slot s = (gen<<48) | key_s
  //   key = (distbits<<16)|(idx^0xFFFF); coords re-fetched from pcs by idx.
  ull* myslots = slots + (size_t)beta * (2 * BPB * 4);

  int e = 0;            // exchange counter == gen (1..E, E<=39)
  int sbase = 0;        // first seed index of pending batch
  int pcnt  = 1;        // pending batch size
  while (sbase + pcnt < NSEED) {
    ++e;
    const int pp  = (e - 1) & 1;      // parity holding pending batch
    const int par = e & 1;            // parity for this exchange's outputs

    // ---- phase A: min-update with all pending centroids (exact float path) ----
    for (int i = 0; i < pcnt; ++i) {
      const float cx = sWx[pp][i], cy = sWy[pp][i], cz = sWz[pp][i];
#pragma unroll
      for (int j = 0; j < PPT; ++j) {
        float dx = px[j] - cx, dy = py[j] - cy, dz = pz[j] - cz;
        float d  = __fadd_rn(__fadd_rn(__fmul_rn(dx, dx), __fmul_rn(dy, dy)),
                             __fmul_rn(dz, dz));
        dist[j] = fminf(dist[j], d);
      }
    }

    // ---- phase A2: per-wave top-4 keys (exclusion re-scan + butterfly) ----
    ull kk[PPT];
#pragma unroll
    for (int j = 0; j < PPT; ++j) {
      int n = blk * (TPB * PPT) + j * TPB + tid;
      kk[j] = packdi(dist[j], n);
    }
    ull s0, s1, s2, s3;
    { ull b = 0;
#pragma unroll
      for (int j = 0; j < PPT; ++j) b = kk[j] > b ? kk[j] : b;
      s0 = bmax64(b); }
    { ull b = 0;
#pragma unroll
      for (int j = 0; j < PPT; ++j) { ull k = kk[j]; if (k != s0 && k > b) b = k; }
      s1 = bmax64(b); }
    { ull b = 0;
#pragma unroll
      for (int j = 0; j < PPT; ++j) { ull k = kk[j]; if (k != s0 && k != s1 && k > b) b = k; }
      s2 = bmax64(b); }
    { ull b = 0;
#pragma unroll
      for (int j = 0; j < PPT; ++j) { ull k = kk[j]; if (k != s0 && k != s1 && k != s2 && k > b) b = k; }
      s3 = bmax64(b); }
    if (lane == 0) {
      sRedP[par][wav][0] = s0; sRedP[par][wav][1] = s1;
      sRedP[par][wav][2] = s2; sRedP[par][wav][3] = s3;
    }
    __syncthreads();   // barrier 1: sRed complete

    const ull gen = (ull)e;
    const ull g48 = gen << 48;
    ull* arr = myslots + (size_t)par * (BPB * 4);

    if (wav == 0) {
      // ---- merge 64 wave-candidates -> block top-4, publish 4 words ----
      ull c = sRedP[par][lane >> 2][lane & 3];
      ull m0 = bmax64(c);
      ull m1 = bmax64(c == m0 ? 0 : c);
      ull m2 = bmax64((c == m0 || c == m1) ? 0 : c);
      ull m3 = bmax64((c == m0 || c == m1 || c == m2) ? 0 : c);
      ull rec = g48 | (m0 & PAYLOAD);
      if (lane == 1) rec = g48 | (m1 & PAYLOAD);
      if (lane == 2) rec = g48 | (m2 & PAYLOAD);
      if (lane == 3) rec = g48 | (m3 & PAYLOAD);
      if (lane < 4)
        __hip_atomic_store(&arr[blk * 4 + lane], rec,
                           __ATOMIC_RELAXED, __HIP_MEMORY_SCOPE_AGENT);

      // 2-deep pipelined poll (unchanged discipline)
      ull vcur = __hip_atomic_load(&arr[lane], __ATOMIC_RELAXED,
                                   __HIP_MEMORY_SCOPE_AGENT);
      for (;;) {
        ull vnext = __hip_atomic_load(&arr[lane], __ATOMIC_RELAXED,
                                      __HIP_MEMORY_SCOPE_AGENT);
        if (__all((int)((vcur >> 48) == gen))) break;
        vcur = vnext;
      }
      ull p = vcur & PAYLOAD;          // lane's candidate key (block lane>>2, rank lane&3)

      // floor F = max over blocks of their 4th key: every unpublished point < F
      ull F = bmax64(((lane & 3) == 3) ? p : 0);
      bool alive = (p >= F);           // live set: every key >= F is published
      float qx = 0.f, qy = 0.f, qz = 0.f;
      if (alive) {                     // refetch exact coords (read-only, L3-resident)
        int idx = (int)((p ^ 0xFFFFull) & 0xFFFFull);
        const float* q = base + 3 * idx;
        qx = q[0]; qy = q[1]; qz = q[2];
      }

      // ---- cascade: accept while provable (updated max key >= F) ----
      ull ck = p;
      int acc = 0;
      int maxacc = NSEED - (sbase + pcnt);
      if (maxacc > MAXACC) maxacc = MAXACC;
      while (acc < maxacc) {
        ull wk = bmax64(alive ? ck : 0);
        if (wk < F) break;                                  // can no longer prove
        ull bal = __ballot(alive && (ck == wk));
        int src = __ffsll((long long)bal) - 1;
        float wx = __shfl(qx, src, 64);
        float wy = __shfl(qy, src, 64);
        float wz = __shfl(qz, src, 64);
        if (lane == 0) {
          sWx[par][acc] = wx; sWy[par][acc] = wy; sWz[par][acc] = wz;
          int sidx = sbase + pcnt + acc;
          sSx[sidx] = wx; sSy[sidx] = wy; sSz[sidx] = wz;
        }
        if (lane == src) alive = false;
        if (alive) {                   // bit-identical to block min-update path
          float dx = qx - wx, dy = qy - wy, dz = qz - wz;
          float d  = __fadd_rn(__fadd_rn(__fmul_rn(dx, dx), __fmul_rn(dy, dy)),
                               __fmul_rn(dz, dz));
          float cd = __uint_as_float((unsigned)(ck >> 16));
          if (d < cd) ck = ((ull)__float_as_uint(d) << 16) | (ck & 0xFFFFull);
        }
        ++acc;
      }
      if (lane == 0) sWn[par] = acc;
    } else {
      // ---- waves 1..15: density for the pending batch, hidden in poll window ----
      for (int i = 0; i < pcnt; ++i) {
        const float cx = sWx[pp][i], cy = sWy[pp][i], cz = sWz[pp][i];
        float da = 0.f;
#pragma unroll
        for (int j = 0; j < PPT; ++j) {
          float dx = px[j] - cx, dy = py[j] - cy, dz = pz[j] - cz;
          float d  = dx * dx + dy * dy + dz * dz;
          da += fmaxf(R2 - d, 0.f);
        }
#pragma unroll
        for (int o = 32; o > 0; o >>= 1) da += __shfl_xor(da, o, 64);
        if (lane == 0) sDen[wav][sbase + i] = da;
      }
    }
    __syncthreads();   // barrier 2: accepted batch published
    sbase += pcnt;
    pcnt = sWn[par];
  }

  // ---- density tails ----
  if (wav == 0) {
    for (int s = 0; s < NSEED; ++s) {   // wave 0: all seeds, replayed from LDS
      float sx = sSx[s], sy = sSy[s], sz = sSz[s];
      float a = 0.f;
#pragma unroll
      for (int j = 0; j < PPT; ++j) {
        float dx = px[j] - sx, dy = py[j] - sy, dz = pz[j] - sz;
        float d  = dx * dx + dy * dy + dz * dz;
        a += fmaxf(R2 - d, 0.f);
      }
#pragma unroll
      for (int o = 32; o > 0; o >>= 1) a += __shfl_xor(a, o, 64);
      if (lane == 0) sDen[0][s] = a;
    }
  } else {
    const int fp = e & 1;               // parity of final accepted batch
    for (int i = 0; i < pcnt; ++i) {    // waves 1..15: final batch
      const float cx = sWx[fp][i], cy = sWy[fp][i], cz = sWz[fp][i];
      float a = 0.f;
#pragma unroll
      for (int j = 0; j < PPT; ++j) {
        float dx = px[j] - cx, dy = py[j] - cy, dz = pz[j] - cz;
        float d  = dx * dx + dy * dy + dz * dz;
        a += fmaxf(R2 - d, 0.f);
      }
#pragma unroll
      for (int o = 32; o > 0; o >>= 1) a += __shfl_xor(a, o, 64);
      if (lane == 0) sDen[wav][sbase + i] = a;
    }
  }
  __syncthreads();

  // ---- publish per-block density partials as gen-tagged, self-validating words
  if (tid < NSEED) {
    float t = 0.f;
#pragma unroll
    for (int w = 0; w < NW; ++w) t += sDen[w][tid];
    ull rec = (DONEG << 48) | (ull)__float_as_uint(t);
    __hip_atomic_store(&pden[((size_t)beta * BPB + blk) * NSEED + tid], rec,
                       __ATOMIC_RELAXED, __HIP_MEMORY_SCOPE_AGENT);
  }

  // ---- block 0: fused variance epilogue (saves the second dispatch) ----
  if (blockIdx.x == 0) {
    __syncthreads();   // barrier drains vmcnt: own pden stores are committed
    if (tid < NB * NSEED) {
      int b0 = tid / NSEED, s = tid - b0 * NSEED;   // (batch, seed)
      float a = 0.f;
#pragma unroll
      for (int c = 0; c < 2; ++c) {                 // 2 chunks of 8 pipelined loads
        ull v[8];
#pragma unroll
        for (int b = 0; b < 8; ++b)
          v[b] = __hip_atomic_load(
              &pden[((size_t)b0 * BPB + c * 8 + b) * NSEED + s],
              __ATOMIC_RELAXED, __HIP_MEMORY_SCOPE_AGENT);
        for (;;) {                                   // retry only invalid words
          bool ok = true;
#pragma unroll
          for (int b = 0; b < 8; ++b)
            if ((v[b] >> 48) != DONEG) {
              ok = false;
              v[b] = __hip_atomic_load(
                  &pden[((size_t)b0 * BPB + c * 8 + b) * NSEED + s],
                  __ATOMIC_RELAXED, __HIP_MEMORY_SCOPE_AGENT);
            }
          if (ok) break;
        }
#pragma unroll
        for (int b = 0; b < 8; ++b)
          a += __uint_as_float((unsigned)(v[b] & 0xFFFFFFFFull));
      }
      sDen[b0][s] = a;   // reuse sDen as the 16x40 density matrix
    }
    __syncthreads();
    if (tid < NB) {
      float m = 0.f;
      for (int s = 0; s < NSEED; ++s) m += sDen[tid][s];
      m /= (float)NSEED;
      float q = 0.f;
      for (int s = 0; s < NSEED; ++s) { float d = sDen[tid][s] - m; q += d * d; }
      sV[tid] = q / (float)(NSEED - 1);   // ddof=1
    }
    __syncthreads();
    if (tid == 0) {
      float v = 0.f;
      for (int i = 0; i < NB; ++i) v += sV[i];
      out[0] = v / (float)NB;
    }
  }
}

extern "C" void kernel_launch(void* const* d_in, const int* in_sizes, int n_in,
                              void* d_out, int out_size, void* d_ws, size_t ws_size,
                              hipStream_t stream) {
  const float* pcs = (const float*)d_in[0];
  float* out  = (float*)d_out;
  ull*   pden = (ull*)d_ws;                         // 16*16*40*8 = 81920 B
  ull*   slots = (ull*)((char*)d_ws + 81920);       // 16*2*16*4*8 = 16384 B
  fps_den_kernel<<<dim3(NB * BPB), dim3(TPB), 0, stream>>>(pcs, slots, pden, out);
}